// Round 8
// baseline (2292.846 us; speedup 1.0000x reference)
//
#include <hip/hip_runtime.h>
#include <cstdint>
#include <cstddef>

#define T_STEPS 1024
#define NB 64
#define DIN 256
#define DH 256
#define DW 512            // DIN + DH (row width of each W)
#define G4 1024           // 4*DH gate rows

typedef _Float16 h2 __attribute__((ext_vector_type(2)));
typedef _Float16 h4 __attribute__((ext_vector_type(4)));
typedef _Float16 h8 __attribute__((ext_vector_type(8)));
typedef float f4 __attribute__((ext_vector_type(4)));

// Build h2 = (v[2m], v[2m+1]). Dynamic subscripts constant-fold after unroll.
static __device__ __forceinline__ h2 sl2(h8 v, int m) {
  h2 r; r[0] = v[2 * m]; r[1] = v[2 * m + 1]; return r;
}
static __device__ __forceinline__ h2 sl2_4(h4 v, int m) {
  h2 r; r[0] = v[2 * m]; r[1] = v[2 * m + 1]; return r;
}

static __device__ __forceinline__ float fdot2(h2 a, h2 b, float c) {
#if __has_builtin(__builtin_amdgcn_fdot2)
  return __builtin_amdgcn_fdot2(a, b, c, false);
#else
  return c + (float)a[0]*(float)b[0] + (float)a[1]*(float)b[1];
#endif
}

static __device__ __forceinline__ float rcp_(float x) {
#if __has_builtin(__builtin_amdgcn_rcpf)
  return __builtin_amdgcn_rcpf(x);
#else
  return 1.0f / x;
#endif
}

static __device__ __forceinline__ float sigmoid_(float x) {
  x = fminf(fmaxf(x, -30.f), 30.f);
  return rcp_(1.f + __expf(-x));
}
static __device__ __forceinline__ float tanh_(float x) {
  x = fminf(fmaxf(x, -15.f), 15.f);
  float e = __expf(2.f * x);
  return 1.f - 2.f * rcp_(e + 1.f);
}

// DPP quad-perm swaps: xor-1 ([1,0,3,2] = 0xB1) and xor-2 ([2,3,0,1] = 0x4E).
static __device__ __forceinline__ float dpp_swap1(float x) {
  int r = __builtin_amdgcn_update_dpp(0, __builtin_bit_cast(int, x),
                                      0xB1, 0xF, 0xF, true);
  return __builtin_bit_cast(float, r);
}
static __device__ __forceinline__ float dpp_swap2(float x) {
  int r = __builtin_amdgcn_update_dpp(0, __builtin_bit_cast(int, x),
                                      0x4E, 0xF, 0xF, true);
  return __builtin_bit_cast(float, r);
}

// ---------------------------------------------------------------------------
// Weight pre-conversion (unchanged).
//  wxhT[kp][gr]  = x-part, k-pair-major (for kxgemm)
//  wrowh[gr][kp] = h-part, row-major    (for klstm)
// ---------------------------------------------------------------------------
__global__ void kconv_w(const float* __restrict__ Wf, const float* __restrict__ Wi,
                        const float* __restrict__ Wg, const float* __restrict__ Wo,
                        h2* __restrict__ wxhT, h2* __restrict__ wrowh) {
  int kp = blockIdx.x >> 2;
  int gate = blockIdx.x & 3;
  int j = threadIdx.x;
  const float* W = gate == 0 ? Wf : gate == 1 ? Wi : gate == 2 ? Wg : Wo;
  const float* row = W + (size_t)j * DW;
  h2 v; v[0] = (_Float16)row[2*kp]; v[1] = (_Float16)row[2*kp + 1];
  wxhT[(size_t)kp * G4 + gate * DH + j] = v;
  h2 u; u[0] = (_Float16)row[DIN + 2*kp]; u[1] = (_Float16)row[DIN + 2*kp + 1];
  wrowh[((size_t)gate * DH + j) * 128 + kp] = u;
}

// ---------------------------------------------------------------------------
// Phase 1: Xg[t][b][gr] = x[t][b][:] . Wx[gr][:] + bias[gr]   (f16 out)
// (unchanged)
// ---------------------------------------------------------------------------
__launch_bounds__(256, 2)
__global__ void kxgemm(const float* __restrict__ x,
                       const h2* __restrict__ wxhT,
                       const float* __restrict__ bf, const float* __restrict__ bi,
                       const float* __restrict__ bg, const float* __restrict__ bo,
                       _Float16* __restrict__ Xg,
                       int t0) {
  __shared__ h2 xs[64 * 64];
  __shared__ h2 wsT[64 * 256];

  int tid = threadIdx.x;
  int tg = tid & 31, tr = tid >> 5;
  int tb = blockIdx.x >> 2, gb = blockIdx.x & 3;
  size_t xrow0 = ((size_t)(t0 + tb)) * NB;

  float acc[8][8];
#pragma unroll
  for (int r = 0; r < 8; ++r)
#pragma unroll
    for (int g = 0; g < 8; ++g) acc[r][g] = 0.f;

  for (int ks = 0; ks < 2; ++ks) {
#pragma unroll
    for (int i = 0; i < 8; ++i) {
      int idx = tid + 256 * i;
      int r = idx >> 5, k4 = idx & 31;
      f4 v = *(const f4*)(x + (xrow0 + r) * DIN + ks * 128 + k4 * 4);
      h4 p;
      p[0] = (_Float16)v[0]; p[1] = (_Float16)v[1];
      p[2] = (_Float16)v[2]; p[3] = (_Float16)v[3];
      *(h4*)(void*)(xs + (size_t)r * 64 + 2 * k4) = p;
    }
#pragma unroll
    for (int i = 0; i < 16; ++i) {
      int idx = tid + 256 * i;
      int kp = idx >> 6, g4 = idx & 63;
      f4 v = *(const f4*)(const void*)(wxhT + (size_t)(ks * 64 + kp) * G4 + gb * DH + g4 * 4);
      *(f4*)(void*)(wsT + (size_t)kp * 256 + g4 * 4) = v;
    }
    __syncthreads();

#pragma unroll 2
    for (int kp2 = 0; kp2 < 32; ++kp2) {
      h4 xv[8];
#pragma unroll
      for (int r = 0; r < 8; ++r)
        xv[r] = *(const h4*)(const void*)(xs + (size_t)(tr * 8 + r) * 64 + 2 * kp2);
      h8 w0a = *(const h8*)(const void*)(wsT + (size_t)(2 * kp2) * 256 + tg * 8);
      h8 w0b = *(const h8*)(const void*)(wsT + (size_t)(2 * kp2) * 256 + tg * 8 + 4);
      h8 w1a = *(const h8*)(const void*)(wsT + (size_t)(2 * kp2 + 1) * 256 + tg * 8);
      h8 w1b = *(const h8*)(const void*)(wsT + (size_t)(2 * kp2 + 1) * 256 + tg * 8 + 4);
#pragma unroll
      for (int r = 0; r < 8; ++r) {
        h2 x0 = sl2_4(xv[r], 0);
        h2 x1 = sl2_4(xv[r], 1);
#pragma unroll
        for (int g = 0; g < 4; ++g) {
          acc[r][g] = fdot2(x0, sl2(w0a, g), acc[r][g]);
          acc[r][g] = fdot2(x1, sl2(w1a, g), acc[r][g]);
        }
#pragma unroll
        for (int g = 0; g < 4; ++g) {
          acc[r][4 + g] = fdot2(x0, sl2(w0b, g), acc[r][4 + g]);
          acc[r][4 + g] = fdot2(x1, sl2(w1b, g), acc[r][4 + g]);
        }
      }
    }
    __syncthreads();
  }

  const float* bias = gb == 0 ? bf : gb == 1 ? bi : gb == 2 ? bg : bo;
  float bv[8];
#pragma unroll
  for (int g = 0; g < 8; ++g) bv[g] = bias[tg * 8 + g];
#pragma unroll
  for (int r = 0; r < 8; ++r) {
    h8 o;
#pragma unroll
    for (int g = 0; g < 8; ++g) o[g] = (_Float16)(acc[r][g] + bv[g]);
    *(h8*)(void*)(Xg + ((size_t)tb * NB + tr * 8 + r) * G4 + gb * DH + tg * 8) = o;
  }
}

// ---------------------------------------------------------------------------
// Phase 2: sequential LSTM. One workgroup per batch (sync-free), 1024 threads
// (16 waves: HW cap = 128 VGPR/wave; per-thread demand ~122 => grant==demand,
// no overflow). Thread (j = tid>>2, p = tid&3) owns all 4 gate rows of unit j
// over K-quarter p (64 h): chunks 0..5 (24 h8 = 96 VGPR, asm-pinned) in regs,
// chunks 6..7 in LDS (128KB). K-quarter partials combined via 2-stage DPP
// quad butterfly. hbuf quarters skewed by 4 h2 (stride 36) => the 4 broadcast
// addresses of a wave start on banks 0/4/8/12 — conflict-free.
// x: ONE b16 load/thread (lane p takes gate p), prefetched one step ahead.
// ---------------------------------------------------------------------------
#define CH6(M) M(0) M(1) M(2) M(3) M(4) M(5)
#define HQ 36   // h2 stride of one K-quarter in hbuf (32 + 4 skew)

__global__ __launch_bounds__(1024, 1)
void klstm(const h2* __restrict__ wrowh,
           const _Float16* __restrict__ Xg,
           const float* __restrict__ hsrc, const float* __restrict__ csrc,
           float* __restrict__ out,
           float* __restrict__ hN, float* __restrict__ cN,
           int t0, int Tc) {
  __shared__ h8 wtail[8][1024];   // 128KB: [gate*2 + (chunk-6)][tid]
  __shared__ h2 hbuf[2][4 * HQ];  // double-buffered h, quarters skewed

  int tid = threadIdx.x;
  int b = blockIdx.x;
  int p = tid & 3;
  int j = tid >> 2;

  const h2* rowF = wrowh + ((size_t)0 * DH + j) * 128 + p * 32;
  const h2* rowI = wrowh + ((size_t)1 * DH + j) * 128 + p * 32;
  const h2* rowG = wrowh + ((size_t)2 * DH + j) * 128 + p * 32;
  const h2* rowO = wrowh + ((size_t)3 * DH + j) * 128 + p * 32;

  // --- weights: chunks 0..5 per gate row in named registers, asm-pinned ---
#define DECLW(c) h8 WF_##c, WI_##c, WG_##c, WO_##c;
  CH6(DECLW)
#undef DECLW
#define LOADW(c) \
  WF_##c = *(const h8*)(const void*)(rowF + 4 * (c)); \
  WI_##c = *(const h8*)(const void*)(rowI + 4 * (c)); \
  WG_##c = *(const h8*)(const void*)(rowG + 4 * (c)); \
  WO_##c = *(const h8*)(const void*)(rowO + 4 * (c));
  CH6(LOADW)
#undef LOADW
#define PINW(c) \
  asm volatile("" : "+v"(WF_##c)); asm volatile("" : "+v"(WI_##c)); \
  asm volatile("" : "+v"(WG_##c)); asm volatile("" : "+v"(WO_##c));
  CH6(PINW)
#undef PINW

  // --- tail chunks 6..7 per gate row -> LDS ---
#pragma unroll
  for (int tt = 0; tt < 2; ++tt) {
    wtail[0 + tt][tid] = *(const h8*)(const void*)(rowF + 24 + 4 * tt);
    wtail[2 + tt][tid] = *(const h8*)(const void*)(rowI + 24 + 4 * tt);
    wtail[4 + tt][tid] = *(const h8*)(const void*)(rowG + 24 + 4 * tt);
    wtail[6 + tt][tid] = *(const h8*)(const void*)(rowO + 24 + 4 * tt);
  }

  float creg = csrc[(size_t)b * DH + j];  // replicated across the quad
  if (tid < 128) {
    // tid = h2 index of h0; quarter q = tid>>5, skewed position q*HQ + (tid&31)
    int pos = (tid >> 5) * HQ + (tid & 31);
    h2 hv;
    hv[0] = (_Float16)hsrc[(size_t)b * DH + 2 * tid];
    hv[1] = (_Float16)hsrc[(size_t)b * DH + 2 * tid + 1];
    hbuf[0][pos] = hv;
  }
  __syncthreads();

  const size_t xstep = (size_t)NB * G4;
  // lane p of the quad owns the x-part of gate p, row j
  const _Float16* xp = Xg + (size_t)b * G4 + p * DH + j;
  float xcur = (float)xp[0];
  float hlast = 0.f;

  for (int t = 0; t < Tc; ++t) {
    // prefetch next step's x early so L2 latency hides under the dot work
    float xnext = (t + 1 < Tc) ? (float)xp[(size_t)(t + 1) * xstep] : 0.f;
    const h2* hb = hbuf[t & 1] + p * HQ;

    // x counted once per gate: lane p seeds gate p's partial
    float accF = (p == 0) ? xcur : 0.f;
    float accI = (p == 1) ? xcur : 0.f;
    float accG = (p == 2) ? xcur : 0.f;
    float accO = (p == 3) ? xcur : 0.f;

#define DOTCH(c) { \
    h8 hv = *(const h8*)(const void*)(hb + 4 * (c)); \
    accF = fdot2(sl2(WF_##c,0), sl2(hv,0), accF); \
    accF = fdot2(sl2(WF_##c,1), sl2(hv,1), accF); \
    accF = fdot2(sl2(WF_##c,2), sl2(hv,2), accF); \
    accF = fdot2(sl2(WF_##c,3), sl2(hv,3), accF); \
    accI = fdot2(sl2(WI_##c,0), sl2(hv,0), accI); \
    accI = fdot2(sl2(WI_##c,1), sl2(hv,1), accI); \
    accI = fdot2(sl2(WI_##c,2), sl2(hv,2), accI); \
    accI = fdot2(sl2(WI_##c,3), sl2(hv,3), accI); \
    accG = fdot2(sl2(WG_##c,0), sl2(hv,0), accG); \
    accG = fdot2(sl2(WG_##c,1), sl2(hv,1), accG); \
    accG = fdot2(sl2(WG_##c,2), sl2(hv,2), accG); \
    accG = fdot2(sl2(WG_##c,3), sl2(hv,3), accG); \
    accO = fdot2(sl2(WO_##c,0), sl2(hv,0), accO); \
    accO = fdot2(sl2(WO_##c,1), sl2(hv,1), accO); \
    accO = fdot2(sl2(WO_##c,2), sl2(hv,2), accO); \
    accO = fdot2(sl2(WO_##c,3), sl2(hv,3), accO); }
    CH6(DOTCH)
#undef DOTCH
#pragma unroll
    for (int tt = 0; tt < 2; ++tt) {
      h8 hv = *(const h8*)(const void*)(hb + 24 + 4 * tt);
      h8 wf = wtail[0 + tt][tid];
      h8 wi = wtail[2 + tt][tid];
      h8 wg = wtail[4 + tt][tid];
      h8 wo = wtail[6 + tt][tid];
#pragma unroll
      for (int m = 0; m < 4; ++m) {
        accF = fdot2(sl2(wf, m), sl2(hv, m), accF);
        accI = fdot2(sl2(wi, m), sl2(hv, m), accI);
        accG = fdot2(sl2(wg, m), sl2(hv, m), accG);
        accO = fdot2(sl2(wo, m), sl2(hv, m), accO);
      }
    }

    // combine K-quarters across the quad: 2-stage DPP butterfly (no LDS)
    accF += dpp_swap1(accF); accI += dpp_swap1(accI);
    accG += dpp_swap1(accG); accO += dpp_swap1(accO);
    accF += dpp_swap2(accF); accI += dpp_swap2(accI);
    accG += dpp_swap2(accG); accO += dpp_swap2(accO);

    float f_ = sigmoid_(accF);
    float i_ = sigmoid_(accI);
    float g_ = tanh_(accG);
    float o_ = sigmoid_(accO);

    creg = f_ * creg + i_ * g_;
    float hn = o_ * tanh_(creg);
    hlast = hn;
    if (p == 0) {
      out[((size_t)(t0 + t) * NB + b) * DH + j] = hn;
    } else if (p == 1) {
      // h element j -> skewed f16 position: quarter j>>6, within j&63
      int pos = (j >> 6) * (2 * HQ) + (j & 63);
      ((_Float16*)hbuf[(t + 1) & 1])[pos] = (_Float16)hn;
    }
    __syncthreads();
    xcur = xnext;
  }

  if (p == 0) {
    hN[(size_t)b * DH + j] = hlast;
    cN[(size_t)b * DH + j] = creg;
  }
}

// ---------------------------------------------------------------------------
extern "C" void kernel_launch(void* const* d_in, const int* in_sizes, int n_in,
                              void* d_out, int out_size, void* d_ws, size_t ws_size,
                              hipStream_t stream) {
  if (n_in < 11) return;
  const float* x  = (const float*)d_in[0];
  const float* h0 = (const float*)d_in[1];
  const float* c0 = (const float*)d_in[2];
  const float* Wf = (const float*)d_in[3];
  const float* bf = (const float*)d_in[4];
  const float* Wi = (const float*)d_in[5];
  const float* bi = (const float*)d_in[6];
  const float* Wg = (const float*)d_in[7];
  const float* bg = (const float*)d_in[8];
  const float* Wo = (const float*)d_in[9];
  const float* bo = (const float*)d_in[10];

  float* out = (float*)d_out;
  float* hN = out + (size_t)T_STEPS * NB * DH;
  float* cN = hN + (size_t)NB * DH;

  // ws layout: [Xg ring: Tc*128KB][wxhT 512KB][wrowh 512KB]
  const size_t wxhBytes = (size_t)128 * G4 * sizeof(h2);   // 512KB
  const size_t wrowBytes = (size_t)G4 * 128 * sizeof(h2);  // 512KB
  const size_t fixedBytes = wxhBytes + wrowBytes;
  size_t avail = (ws_size > fixedBytes + 256) ? ws_size - fixedBytes - 256 : 0;
  const size_t perT = (size_t)NB * G4 * 2;  // 128KB per time step
  int Tc = (int)(avail / perT);
  if (Tc > T_STEPS) Tc = T_STEPS;
  if (Tc < 1) Tc = 1;

  _Float16* Xg = (_Float16*)d_ws;
  size_t xgBytes = ((size_t)Tc * perT + 255) / 256 * 256;
  h2* wxhT = (h2*)((char*)d_ws + xgBytes);
  h2* wrowh = (h2*)((char*)d_ws + xgBytes + wxhBytes);

  kconv_w<<<dim3(512), dim3(256), 0, stream>>>(Wf, Wi, Wg, Wo, wxhT, wrowh);

  for (int t0 = 0; t0 < T_STEPS; t0 += Tc) {
    int tc = (T_STEPS - t0 < Tc) ? (T_STEPS - t0) : Tc;
    kxgemm<<<dim3(tc * 4), dim3(256), 0, stream>>>(x, wxhT, bf, bi, bg, bo, Xg, t0);
    const float* hs = (t0 == 0) ? h0 : hN;
    const float* cs = (t0 == 0) ? c0 : cN;
    klstm<<<dim3(NB), dim3(1024), 0, stream>>>(wrowh, Xg, hs, cs,
                                               out, hN, cN, t0, tc);
  }
}

// Round 9
// 1991.015 us; speedup vs baseline: 1.1516x; 1.1516x over previous
//
#include <hip/hip_runtime.h>
#include <cstdint>
#include <cstddef>

#define T_STEPS 1024
#define NB 64
#define DIN 256
#define DH 256
#define DW 512            // DIN + DH (row width of each W)
#define G4 1024           // 4*DH gate rows

typedef _Float16 h2 __attribute__((ext_vector_type(2)));
typedef _Float16 h4 __attribute__((ext_vector_type(4)));
typedef _Float16 h8 __attribute__((ext_vector_type(8)));
typedef float f4 __attribute__((ext_vector_type(4)));

// Build h2 = (v[2m], v[2m+1]). Dynamic subscripts constant-fold after unroll.
static __device__ __forceinline__ h2 sl2(h8 v, int m) {
  h2 r; r[0] = v[2 * m]; r[1] = v[2 * m + 1]; return r;
}
static __device__ __forceinline__ h2 sl2_4(h4 v, int m) {
  h2 r; r[0] = v[2 * m]; r[1] = v[2 * m + 1]; return r;
}

static __device__ __forceinline__ float fdot2(h2 a, h2 b, float c) {
#if __has_builtin(__builtin_amdgcn_fdot2)
  return __builtin_amdgcn_fdot2(a, b, c, false);
#else
  return c + (float)a[0]*(float)b[0] + (float)a[1]*(float)b[1];
#endif
}

static __device__ __forceinline__ float rcp_(float x) {
#if __has_builtin(__builtin_amdgcn_rcpf)
  return __builtin_amdgcn_rcpf(x);
#else
  return 1.0f / x;
#endif
}

static __device__ __forceinline__ float sigmoid_(float x) {
  x = fminf(fmaxf(x, -30.f), 30.f);
  return rcp_(1.f + __expf(-x));
}
static __device__ __forceinline__ float tanh_(float x) {
  x = fminf(fmaxf(x, -15.f), 15.f);
  float e = __expf(2.f * x);
  return 1.f - 2.f * rcp_(e + 1.f);
}

// Pairwise lane swap (0<->1, 2<->3, ...) via DPP quad_perm [1,0,3,2] — pure
// VALU, no LDS-pipe traffic.
static __device__ __forceinline__ float dpp_swap1(float x) {
#if __has_builtin(__builtin_amdgcn_update_dpp)
  int r = __builtin_amdgcn_update_dpp(0, __builtin_bit_cast(int, x),
                                      0xB1, 0xF, 0xF, true);
  return __builtin_bit_cast(float, r);
#else
  return __shfl_xor(x, 1);
#endif
}

// ---------------------------------------------------------------------------
// Weight pre-conversion (unchanged).
//  wxhT[kp][gr]  = x-part, k-pair-major (for kxgemm)
//  wrowh[gr][kp] = h-part, row-major    (for klstm)
// ---------------------------------------------------------------------------
__global__ void kconv_w(const float* __restrict__ Wf, const float* __restrict__ Wi,
                        const float* __restrict__ Wg, const float* __restrict__ Wo,
                        h2* __restrict__ wxhT, h2* __restrict__ wrowh) {
  int kp = blockIdx.x >> 2;
  int gate = blockIdx.x & 3;
  int j = threadIdx.x;
  const float* W = gate == 0 ? Wf : gate == 1 ? Wi : gate == 2 ? Wg : Wo;
  const float* row = W + (size_t)j * DW;
  h2 v; v[0] = (_Float16)row[2*kp]; v[1] = (_Float16)row[2*kp + 1];
  wxhT[(size_t)kp * G4 + gate * DH + j] = v;
  h2 u; u[0] = (_Float16)row[DIN + 2*kp]; u[1] = (_Float16)row[DIN + 2*kp + 1];
  wrowh[((size_t)gate * DH + j) * 128 + kp] = u;
}

// ---------------------------------------------------------------------------
// Phase 1: Xg[t][b][gr] = x[t][b][:] . Wx[gr][:] + bias[gr]   (f16 out)
// (unchanged)
// ---------------------------------------------------------------------------
__launch_bounds__(256, 2)
__global__ void kxgemm(const float* __restrict__ x,
                       const h2* __restrict__ wxhT,
                       const float* __restrict__ bf, const float* __restrict__ bi,
                       const float* __restrict__ bg, const float* __restrict__ bo,
                       _Float16* __restrict__ Xg,
                       int t0) {
  __shared__ h2 xs[64 * 64];
  __shared__ h2 wsT[64 * 256];

  int tid = threadIdx.x;
  int tg = tid & 31, tr = tid >> 5;
  int tb = blockIdx.x >> 2, gb = blockIdx.x & 3;
  size_t xrow0 = ((size_t)(t0 + tb)) * NB;

  float acc[8][8];
#pragma unroll
  for (int r = 0; r < 8; ++r)
#pragma unroll
    for (int g = 0; g < 8; ++g) acc[r][g] = 0.f;

  for (int ks = 0; ks < 2; ++ks) {
#pragma unroll
    for (int i = 0; i < 8; ++i) {
      int idx = tid + 256 * i;
      int r = idx >> 5, k4 = idx & 31;
      f4 v = *(const f4*)(x + (xrow0 + r) * DIN + ks * 128 + k4 * 4);
      h4 p;
      p[0] = (_Float16)v[0]; p[1] = (_Float16)v[1];
      p[2] = (_Float16)v[2]; p[3] = (_Float16)v[3];
      *(h4*)(void*)(xs + (size_t)r * 64 + 2 * k4) = p;
    }
#pragma unroll
    for (int i = 0; i < 16; ++i) {
      int idx = tid + 256 * i;
      int kp = idx >> 6, g4 = idx & 63;
      f4 v = *(const f4*)(const void*)(wxhT + (size_t)(ks * 64 + kp) * G4 + gb * DH + g4 * 4);
      *(f4*)(void*)(wsT + (size_t)kp * 256 + g4 * 4) = v;
    }
    __syncthreads();

#pragma unroll 2
    for (int kp2 = 0; kp2 < 32; ++kp2) {
      h4 xv[8];
#pragma unroll
      for (int r = 0; r < 8; ++r)
        xv[r] = *(const h4*)(const void*)(xs + (size_t)(tr * 8 + r) * 64 + 2 * kp2);
      h8 w0a = *(const h8*)(const void*)(wsT + (size_t)(2 * kp2) * 256 + tg * 8);
      h8 w0b = *(const h8*)(const void*)(wsT + (size_t)(2 * kp2) * 256 + tg * 8 + 4);
      h8 w1a = *(const h8*)(const void*)(wsT + (size_t)(2 * kp2 + 1) * 256 + tg * 8);
      h8 w1b = *(const h8*)(const void*)(wsT + (size_t)(2 * kp2 + 1) * 256 + tg * 8 + 4);
#pragma unroll
      for (int r = 0; r < 8; ++r) {
        h2 x0 = sl2_4(xv[r], 0);
        h2 x1 = sl2_4(xv[r], 1);
#pragma unroll
        for (int g = 0; g < 4; ++g) {
          acc[r][g] = fdot2(x0, sl2(w0a, g), acc[r][g]);
          acc[r][g] = fdot2(x1, sl2(w1a, g), acc[r][g]);
        }
#pragma unroll
        for (int g = 0; g < 4; ++g) {
          acc[r][4 + g] = fdot2(x0, sl2(w0b, g), acc[r][4 + g]);
          acc[r][4 + g] = fdot2(x1, sl2(w1b, g), acc[r][4 + g]);
        }
      }
    }
    __syncthreads();
  }

  const float* bias = gb == 0 ? bf : gb == 1 ? bi : gb == 2 ? bg : bo;
  float bv[8];
#pragma unroll
  for (int g = 0; g < 8; ++g) bv[g] = bias[tg * 8 + g];
#pragma unroll
  for (int r = 0; r < 8; ++r) {
    h8 o;
#pragma unroll
    for (int g = 0; g < 8; ++g) o[g] = (_Float16)(acc[r][g] + bv[g]);
    *(h8*)(void*)(Xg + ((size_t)tb * NB + tr * 8 + r) * G4 + gb * DH + tg * 8) = o;
  }
}

// ---------------------------------------------------------------------------
// Phase 2: sequential LSTM. One workgroup per batch (sync-free), 512 threads.
// Thread (j = tid>>1, p = tid&1) holds ALL FOUR gate rows of unit j over its
// K-half: 12 h8 chunks/row in NAMED asm-pinned registers (48 h8 = 192 VGPR),
// 4 h8/row in LDS (128KB). SINGLE CHANGE vs r7: amdgpu_num_vgpr(256) —
// directly overrides the allocator's occupancy-driven grant (empirical rule
// r2-r8: grant = 65536/block_threads, i.e. 128 here, forcing ~97 VGPRs of
// weights into AGPR with per-step copy traffic ~300 VALU instrs/thread).
// 8 waves x 256 VGPR = full per-CU RF, 2 waves/SIMD — legal at 1 block/CU.
// h halves skewed by 4 h2 (16B) so p=0/p=1 broadcast reads hit disjoint banks.
// ---------------------------------------------------------------------------
#define CH12(M) M(0) M(1) M(2) M(3) M(4) M(5) M(6) M(7) M(8) M(9) M(10) M(11)

#define HPAD 68   // h2 stride of one K-half in hbuf (64 + 4 skew)

__global__ __attribute__((amdgpu_flat_work_group_size(512, 512)))
__attribute__((amdgpu_num_vgpr(256)))
void klstm(const h2* __restrict__ wrowh,
           const _Float16* __restrict__ Xg,
           const float* __restrict__ hsrc, const float* __restrict__ csrc,
           float* __restrict__ out,
           float* __restrict__ hN, float* __restrict__ cN,
           int t0, int Tc) {
  __shared__ h8 wtail[16][512];        // 128KB: [row*4 + (chunk-12)][tid]
  __shared__ h2 hbuf[2][2 * HPAD];     // double-buffered h, halves skewed

  int tid = threadIdx.x;
  int b = blockIdx.x;
  int p = tid & 1;
  int j = tid >> 1;
  int hoff = p * HPAD;   // h2 offset of this thread's K-half in hbuf

  const h2* rowF = wrowh + ((size_t)0 * DH + j) * 128 + p * 64;
  const h2* rowI = wrowh + ((size_t)1 * DH + j) * 128 + p * 64;
  const h2* rowG = wrowh + ((size_t)2 * DH + j) * 128 + p * 64;
  const h2* rowO = wrowh + ((size_t)3 * DH + j) * 128 + p * 64;

  // --- weights: chunks 0..11 per row in named registers, asm-pinned ---
#define DECLW(i) h8 WF_##i, WI_##i, WG_##i, WO_##i;
  CH12(DECLW)
#undef DECLW
#define LOADW(i) \
  WF_##i = *(const h8*)(const void*)(rowF + 4 * (i)); \
  WI_##i = *(const h8*)(const void*)(rowI + 4 * (i)); \
  WG_##i = *(const h8*)(const void*)(rowG + 4 * (i)); \
  WO_##i = *(const h8*)(const void*)(rowO + 4 * (i));
  CH12(LOADW)
#undef LOADW
#define PINW(i) \
  asm volatile("" : "+v"(WF_##i)); asm volatile("" : "+v"(WI_##i)); \
  asm volatile("" : "+v"(WG_##i)); asm volatile("" : "+v"(WO_##i));
  CH12(PINW)
#undef PINW

  // --- tail chunks 12..15 per row -> LDS ---
#pragma unroll
  for (int tt = 0; tt < 4; ++tt) {
    wtail[0  + tt][tid] = *(const h8*)(const void*)(rowF + 4 * (12 + tt));
    wtail[4  + tt][tid] = *(const h8*)(const void*)(rowI + 4 * (12 + tt));
    wtail[8  + tt][tid] = *(const h8*)(const void*)(rowG + 4 * (12 + tt));
    wtail[12 + tt][tid] = *(const h8*)(const void*)(rowO + 4 * (12 + tt));
  }

  float creg = csrc[(size_t)b * DH + j];  // replicated across the pair
  if (tid < 128) {
    // tid = h2 index 0..127 of h0; skewed position
    int pos = (tid < 64) ? tid : (HPAD + tid - 64);
    h2 hv;
    hv[0] = (_Float16)hsrc[(size_t)b * DH + 2 * tid];
    hv[1] = (_Float16)hsrc[(size_t)b * DH + 2 * tid + 1];
    hbuf[0][pos] = hv;
  }
  __syncthreads();

  const size_t xstep = (size_t)NB * G4;
  // p=0 loads x-parts of rows {f,i}; p=1 loads {g,o}.
  const _Float16* xpA = Xg + (size_t)b * G4 + p * 512 + j;        // f or g
  const _Float16* xpB = xpA + 256;                                // i or o
  float xA = (float)xpA[0], xB = (float)xpB[0];
  float hlast = 0.f;

  for (int t = 0; t < Tc; ++t) {
    float xAn = 0.f, xBn = 0.f;
    if (t + 1 < Tc) {
      xAn = (float)xpA[(size_t)(t + 1) * xstep];
      xBn = (float)xpB[(size_t)(t + 1) * xstep];
    }
    const h2* hb = hbuf[t & 1] + hoff;

    // init partials with the x-part on the owning lane (counted once)
    float accF = p ? 0.f : xA;
    float accI = p ? 0.f : xB;
    float accG = p ? xA : 0.f;
    float accO = p ? xB : 0.f;

#define DOTCH(i) { \
    h8 hv = *(const h8*)(const void*)(hb + 4 * (i)); \
    accF = fdot2(sl2(WF_##i,0), sl2(hv,0), accF); \
    accF = fdot2(sl2(WF_##i,1), sl2(hv,1), accF); \
    accF = fdot2(sl2(WF_##i,2), sl2(hv,2), accF); \
    accF = fdot2(sl2(WF_##i,3), sl2(hv,3), accF); \
    accI = fdot2(sl2(WI_##i,0), sl2(hv,0), accI); \
    accI = fdot2(sl2(WI_##i,1), sl2(hv,1), accI); \
    accI = fdot2(sl2(WI_##i,2), sl2(hv,2), accI); \
    accI = fdot2(sl2(WI_##i,3), sl2(hv,3), accI); \
    accG = fdot2(sl2(WG_##i,0), sl2(hv,0), accG); \
    accG = fdot2(sl2(WG_##i,1), sl2(hv,1), accG); \
    accG = fdot2(sl2(WG_##i,2), sl2(hv,2), accG); \
    accG = fdot2(sl2(WG_##i,3), sl2(hv,3), accG); \
    accO = fdot2(sl2(WO_##i,0), sl2(hv,0), accO); \
    accO = fdot2(sl2(WO_##i,1), sl2(hv,1), accO); \
    accO = fdot2(sl2(WO_##i,2), sl2(hv,2), accO); \
    accO = fdot2(sl2(WO_##i,3), sl2(hv,3), accO); }
    CH12(DOTCH)
#undef DOTCH
#pragma unroll
    for (int tt = 0; tt < 4; ++tt) {
      h8 hv = *(const h8*)(const void*)(hb + 4 * (12 + tt));
      h8 wf = wtail[0  + tt][tid];
      h8 wi = wtail[4  + tt][tid];
      h8 wg = wtail[8  + tt][tid];
      h8 wo = wtail[12 + tt][tid];
#pragma unroll
      for (int m = 0; m < 4; ++m) {
        accF = fdot2(sl2(wf, m), sl2(hv, m), accF);
        accI = fdot2(sl2(wi, m), sl2(hv, m), accI);
        accG = fdot2(sl2(wg, m), sl2(hv, m), accG);
        accO = fdot2(sl2(wo, m), sl2(hv, m), accO);
      }
    }

    // combine K-halves across the lane pair (DPP, no LDS); both lanes get
    // identical full sums.
    accF += dpp_swap1(accF);
    accI += dpp_swap1(accI);
    accG += dpp_swap1(accG);
    accO += dpp_swap1(accO);

    float f_ = sigmoid_(accF);
    float i_ = sigmoid_(accI);
    float g_ = tanh_(accG);
    float o_ = sigmoid_(accO);

    creg = f_ * creg + i_ * g_;
    float hn = o_ * tanh_(creg);
    hlast = hn;
    if (p == 0) {
      out[((size_t)(t0 + t) * NB + b) * DH + j] = hn;
    } else {
      // skewed write position for h element j
      int pos = (j < 128) ? j : (2 * HPAD + (j - 128));
      ((_Float16*)hbuf[(t + 1) & 1])[pos] = (_Float16)hn;
    }
    __syncthreads();
    xA = xAn; xB = xBn;
  }

  if (p == 0) {
    hN[(size_t)b * DH + j] = hlast;
    cN[(size_t)b * DH + j] = creg;
  }
}

// ---------------------------------------------------------------------------
extern "C" void kernel_launch(void* const* d_in, const int* in_sizes, int n_in,
                              void* d_out, int out_size, void* d_ws, size_t ws_size,
                              hipStream_t stream) {
  if (n_in < 11) return;
  const float* x  = (const float*)d_in[0];
  const float* h0 = (const float*)d_in[1];
  const float* c0 = (const float*)d_in[2];
  const float* Wf = (const float*)d_in[3];
  const float* bf = (const float*)d_in[4];
  const float* Wi = (const float*)d_in[5];
  const float* bi = (const float*)d_in[6];
  const float* Wg = (const float*)d_in[7];
  const float* bg = (const float*)d_in[8];
  const float* Wo = (const float*)d_in[9];
  const float* bo = (const float*)d_in[10];

  float* out = (float*)d_out;
  float* hN = out + (size_t)T_STEPS * NB * DH;
  float* cN = hN + (size_t)NB * DH;

  // ws layout: [Xg ring: Tc*128KB][wxhT 512KB][wrowh 512KB]
  const size_t wxhBytes = (size_t)128 * G4 * sizeof(h2);   // 512KB
  const size_t wrowBytes = (size_t)G4 * 128 * sizeof(h2);  // 512KB
  const size_t fixedBytes = wxhBytes + wrowBytes;
  size_t avail = (ws_size > fixedBytes + 256) ? ws_size - fixedBytes - 256 : 0;
  const size_t perT = (size_t)NB * G4 * 2;  // 128KB per time step
  int Tc = (int)(avail / perT);
  if (Tc > T_STEPS) Tc = T_STEPS;
  if (Tc < 1) Tc = 1;

  _Float16* Xg = (_Float16*)d_ws;
  size_t xgBytes = ((size_t)Tc * perT + 255) / 256 * 256;
  h2* wxhT = (h2*)((char*)d_ws + xgBytes);
  h2* wrowh = (h2*)((char*)d_ws + xgBytes + wxhBytes);

  kconv_w<<<dim3(512), dim3(256), 0, stream>>>(Wf, Wi, Wg, Wo, wxhT, wrowh);

  for (int t0 = 0; t0 < T_STEPS; t0 += Tc) {
    int tc = (T_STEPS - t0 < Tc) ? (T_STEPS - t0) : Tc;
    kxgemm<<<dim3(tc * 4), dim3(256), 0, stream>>>(x, wxhT, bf, bi, bg, bo, Xg, t0);
    const float* hs = (t0 == 0) ? h0 : hN;
    const float* cs = (t0 == 0) ? c0 : cN;
    klstm<<<dim3(NB), dim3(512), 0, stream>>>(wrowh, Xg, hs, cs,
                                              out, hN, cN, t0, tc);
  }
}